// Round 6
// baseline (532.229 us; speedup 1.0000x reference)
//
#include <hip/hip_runtime.h>
#include <stdint.h>

typedef unsigned short u16;
typedef __bf16 bf16x8 __attribute__((ext_vector_type(8)));
typedef float f32x4 __attribute__((ext_vector_type(4)));

__device__ __forceinline__ u16 f2bf(float f) {
  union { float f; unsigned u; } v; v.f = f;
  return (u16)((v.u + 0x7FFFu + ((v.u >> 16) & 1u)) >> 16);
}
__device__ __forceinline__ float bf2f(u16 h) {
  union { unsigned u; float f; } v; v.u = ((unsigned)h) << 16; return v.f;
}

// async 16B global -> LDS (wave-uniform LDS base; HW writes base + lane*16)
__device__ __forceinline__ void gld_lds16(const u16* g, u16* l) {
  uint32_t lo = (uint32_t)(uintptr_t)l;
  lo = __builtin_amdgcn_readfirstlane(lo);
  auto* lp = (__attribute__((address_space(3))) uint32_t*)(uintptr_t)lo;
  auto* gp = (const __attribute__((address_space(1))) uint32_t*)(uintptr_t)g;
  __builtin_amdgcn_global_load_lds(gp, lp, 16, 0, 0);
}

// ---------------- weight fp32 -> bf16 ----------------
__global__ __launch_bounds__(256) void cvt_weights(
    const float* __restrict__ wq, const float* __restrict__ wp,
    u16* __restrict__ oq, u16* __restrict__ op) {
  int i = blockIdx.x * 256 + threadIdx.x;
  if (i < 1536 * 512) oq[i] = f2bf(wq[i]);
  if (i < 512 * 512)  op[i] = f2bf(wp[i]);
}

// ---------------- group norm stats ----------------
__global__ __launch_bounds__(256) void gn_stats(const float* __restrict__ x,
                                                float* __restrict__ stats) {
  int bg = blockIdx.x;  // 0..127
  const float* p = x + (size_t)bg * 65536;
  float s = 0.f, sq = 0.f;
  for (int i = threadIdx.x * 4; i < 65536; i += 1024) {
    float4 v = *(const float4*)(p + i);
    s += v.x + v.y + v.z + v.w;
    sq += v.x * v.x + v.y * v.y + v.z * v.z + v.w * v.w;
  }
  int lane = threadIdx.x & 63, w = threadIdx.x >> 6;
  for (int off = 32; off; off >>= 1) {
    s += __shfl_down(s, off);
    sq += __shfl_down(sq, off);
  }
  __shared__ float ls[4], lq[4];
  if (lane == 0) { ls[w] = s; lq[w] = sq; }
  __syncthreads();
  if (threadIdx.x == 0) {
    float S = ls[0] + ls[1] + ls[2] + ls[3];
    float Q = lq[0] + lq[1] + lq[2] + lq[3];
    float mean = S * (1.f / 65536.f);
    float var = Q * (1.f / 65536.f) - mean * mean;
    stats[bg * 2] = mean;
    stats[bg * 2 + 1] = rsqrtf(var + 1e-6f);
  }
}

// ---------------- group norm + transpose: x[b][c][n] -> xnT[b][n][c] bf16 ----
__global__ __launch_bounds__(256) void gn_norm_t(const float* __restrict__ x,
    const float* __restrict__ stats, const float* __restrict__ gamma,
    const float* __restrict__ beta, u16* __restrict__ xnT) {
  __shared__ u16 tile[64][72];
  int b = blockIdx.z;
  int c0 = blockIdx.y * 64, n0 = blockIdx.x * 64;
  int t = threadIdx.x;
  int cl = t >> 2, ng = (t & 3) * 16;
  int c = c0 + cl;
  float mean = stats[(b * 32 + (c >> 4)) * 2];
  float rstd = stats[(b * 32 + (c >> 4)) * 2 + 1];
  float a = gamma[c] * rstd;
  float b2 = beta[c] - mean * a;
  const float* src = x + ((size_t)b * 512 + c) * 4096 + n0 + ng;
  u16 e[16];
  #pragma unroll
  for (int q = 0; q < 4; ++q) {
    float4 v = *(const float4*)(src + q * 4);
    e[q * 4 + 0] = f2bf(v.x * a + b2);
    e[q * 4 + 1] = f2bf(v.y * a + b2);
    e[q * 4 + 2] = f2bf(v.z * a + b2);
    e[q * 4 + 3] = f2bf(v.w * a + b2);
  }
  #pragma unroll
  for (int j = 0; j < 16; ++j) tile[ng + j][cl] = e[j];
  __syncthreads();
  int nl = t >> 2, cg = (t & 3) * 16;
  uint4 w0 = *(const uint4*)&tile[nl][cg];
  uint4 w1 = *(const uint4*)&tile[nl][cg + 8];
  u16* dst = xnT + ((size_t)b * 4096 + n0 + nl) * 512 + c0 + cg;
  *(uint4*)dst = w0;
  *(uint4*)(dst + 8) = w1;
}

// ---------------- unified NT GEMM: C[m][n] = sum_k A[m*lda+k]*B[n*ldb+k] ----
// 128x128 tile, BK=32, double-buffered LDS + global_load_lds prefetch:
// one barrier per K-iter, next tile's loads in flight during compute.
// bf16 EPIs use an LDS-bounce epilogue (coalesced dwordx4 stores).
// EPI: 2 = bf16 out plain (PV partial)
//      3 = fp32 out + bias[m] + resid (proj; direct epilogue)
//      4 = bf16 out, (acc+bias[n])*scale  (qk: m=spatial, n=channel)
//      5 = bf16 out, acc+bias[m]          (v:  m=channel, n=spatial)
//      7 = bf16 out exp(acc), atomicAdd row-sums into outF[m]
template<int EPI>
__global__ __launch_bounds__(256) void gemm_nt(
    const u16* __restrict__ A, const u16* __restrict__ B,
    int lda, int ldb, int K,
    const float* __restrict__ bias, const float* __restrict__ resid,
    float scale, float* __restrict__ outF, u16* __restrict__ outB, int ldo,
    size_t azs, size_t bzs, size_t ozs) {
  // stages: A0 [0,4096) A1 [4096,8192) B0 [8192,12288) B1 [12288,16384) u16
  // epilogue bounce tile 128x136 overlays [0,17408)
  __shared__ __align__(16) u16 smem[17408];
  const size_t z = blockIdx.z;
  A += z * azs; B += z * bzs;
  const int t = threadIdx.x;
  const int wave = t >> 6, lane = t & 63;
  const int wm = wave >> 1, wn = wave & 1;
  const int quad = lane >> 4, li = lane & 15;
  const int m0 = blockIdx.y * 128, n0 = blockIdx.x * 128;

  const int srow = lane >> 2;
  const int scol = (lane & 3) * 8;
  const u16* gA[2];
  const u16* gB[2];
  int ldsOff[2];  // staging offset of row-block rb within a stage
  #pragma unroll
  for (int r = 0; r < 2; ++r) {
    int rb = wave + 4 * r;
    gA[r] = A + (size_t)(m0 + rb * 16 + srow) * lda + scol;
    gB[r] = B + (size_t)(n0 + rb * 16 + srow) * ldb + scol;
    ldsOff[r] = rb * 512;
  }

  f32x4 zero = {0.f, 0.f, 0.f, 0.f};
  f32x4 acc[4][4];
  #pragma unroll
  for (int i = 0; i < 4; ++i)
    #pragma unroll
    for (int j = 0; j < 4; ++j) acc[i][j] = zero;

  // prologue: tile 0 -> stage 0
  #pragma unroll
  for (int r = 0; r < 2; ++r) {
    gld_lds16(gA[r], &smem[ldsOff[r]]);
    gld_lds16(gB[r], &smem[8192 + ldsOff[r]]);
  }
  __syncthreads();  // drains vmcnt -> stage 0 ready

  for (int kt = 0; kt < K; kt += 32) {
    const int s = (kt >> 5) & 1;
    if (kt + 32 < K) {
      const int ns = s ^ 1;
      #pragma unroll
      for (int r = 0; r < 2; ++r) {
        gld_lds16(gA[r] + kt + 32, &smem[ns * 4096 + ldsOff[r]]);
        gld_lds16(gB[r] + kt + 32, &smem[8192 + ns * 4096 + ldsOff[r]]);
      }
    }
    bf16x8 af[4], bf[4];
    #pragma unroll
    for (int i = 0; i < 4; ++i) {
      af[i] = *(const bf16x8*)&smem[s * 4096 +
               (wm * 64 + i * 16 + li) * 32 + quad * 8];
      bf[i] = *(const bf16x8*)&smem[8192 + s * 4096 +
               (wn * 64 + i * 16 + li) * 32 + quad * 8];
    }
    #pragma unroll
    for (int i = 0; i < 4; ++i)
      #pragma unroll
      for (int j = 0; j < 4; ++j)
        acc[i][j] = __builtin_amdgcn_mfma_f32_16x16x32_bf16(
            af[i], bf[j], acc[i][j], 0, 0, 0);
    __syncthreads();  // all reads of stage s done; prefetch (ns) drained
  }

  if (EPI == 3) {
    // direct fp32 epilogue
    outF += z * ozs; resid += z * ozs;
    #pragma unroll
    for (int i = 0; i < 4; ++i)
      #pragma unroll
      for (int j = 0; j < 4; ++j) {
        int mB = m0 + wm * 64 + i * 16 + quad * 4;
        int n = n0 + wn * 64 + j * 16 + li;
        #pragma unroll
        for (int r = 0; r < 4; ++r) {
          int m = mB + r;
          float v = acc[i][j][r] + bias[m] + resid[(size_t)m * ldo + n];
          outF[(size_t)m * ldo + n] = v;
        }
      }
    return;
  }

  // bf16 epilogues: compute values, bounce through LDS, coalesced stores
  outB += z * ozs;
  #pragma unroll
  for (int i = 0; i < 4; ++i) {
    float rs[4] = {0.f, 0.f, 0.f, 0.f};
    #pragma unroll
    for (int j = 0; j < 4; ++j) {
      int lm = wm * 64 + i * 16 + quad * 4;
      int ln = wn * 64 + j * 16 + li;
      #pragma unroll
      for (int r = 0; r < 4; ++r) {
        float v = acc[i][j][r];
        u16 o;
        if (EPI == 2) {
          o = f2bf(v);
        } else if (EPI == 4) {
          o = f2bf((v + bias[n0 + ln]) * scale);
        } else if (EPI == 5) {
          o = f2bf(v + bias[m0 + lm + r]);
        } else {  // EPI 7
          float e = __expf(v);
          o = f2bf(e);
          rs[r] += e;
        }
        smem[(lm + r) * 136 + ln] = o;
      }
    }
    if (EPI == 7) {
      #pragma unroll
      for (int r = 0; r < 4; ++r) {
        rs[r] += __shfl_xor(rs[r], 1);
        rs[r] += __shfl_xor(rs[r], 2);
        rs[r] += __shfl_xor(rs[r], 4);
        rs[r] += __shfl_xor(rs[r], 8);
      }
      if (li == 0) {
        int mB = m0 + wm * 64 + i * 16 + quad * 4;
        #pragma unroll
        for (int r = 0; r < 4; ++r) atomicAdd(&outF[mB + r], rs[r]);
      }
    }
  }
  __syncthreads();
  {
    int row = t >> 1, half = t & 1;
    const u16* src = &smem[row * 136 + half * 64];
    u16* dst = outB + (size_t)(m0 + row) * ldo + n0 + half * 64;
    #pragma unroll
    for (int cc = 0; cc < 8; ++cc)
      *(uint4*)(dst + cc * 8) = *(const uint4*)(src + cc * 8);
  }
}

// -------- PV split-K reduce: ao = bf16((sum_z part[z]) / rowsum) ----------
__global__ __launch_bounds__(256) void pv_reduce(const u16* __restrict__ part,
    const float* __restrict__ rowsum, u16* __restrict__ ao) {
  size_t i = ((size_t)blockIdx.x * 256 + threadIdx.x) * 4;
  int row = (int)(i >> 9);
  float inv = __builtin_amdgcn_rcpf(rowsum[row]);
  float s0 = 0.f, s1 = 0.f, s2 = 0.f, s3 = 0.f;
  #pragma unroll
  for (int zz = 0; zz < 4; ++zz) {
    ushort4 p = *(const ushort4*)(part + (size_t)zz * 2097152 + i);
    s0 += bf2f(p.x); s1 += bf2f(p.y); s2 += bf2f(p.z); s3 += bf2f(p.w);
  }
  ushort4 o;
  o.x = f2bf(s0 * inv); o.y = f2bf(s1 * inv);
  o.z = f2bf(s2 * inv); o.w = f2bf(s3 * inv);
  *(ushort4*)(ao + i) = o;
}

extern "C" void kernel_launch(void* const* d_in, const int* in_sizes, int n_in,
                              void* d_out, int out_size, void* d_ws, size_t ws_size,
                              hipStream_t stream) {
  (void)in_sizes; (void)n_in; (void)out_size; (void)ws_size;
  const float* x      = (const float*)d_in[0];
  const float* gamma  = (const float*)d_in[1];
  const float* beta   = (const float*)d_in[2];
  const float* w_qkv  = (const float*)d_in[3];
  const float* b_qkv  = (const float*)d_in[4];
  const float* w_proj = (const float*)d_in[5];
  const float* b_proj = (const float*)d_in[6];
  float* out = (float*)d_out;

  const int C = 512, N = 4096;
  const size_t NC = (size_t)N * C;
  const float scale = 0.21022410381342863f;  // 512^-0.25

  char* ws = (char*)d_ws;
  size_t off = 0;
  auto alloc = [&](size_t bytes) -> char* {
    char* p = ws + off; off += (bytes + 255) & ~(size_t)255; return p;
  };
  u16*   wq_bf  = (u16*)alloc((size_t)1536 * 512 * 2);
  u16*   wp_bf  = (u16*)alloc((size_t)512 * 512 * 2);
  float* stats  = (float*)alloc(128 * 2 * 4);
  float* rowsum = (float*)alloc((size_t)4 * N * 4);
  u16*   xnT    = (u16*)alloc((size_t)4 * NC * 2);        // [b][n][c]
  u16*   qkT    = (u16*)alloc((size_t)4 * N * 1024 * 2);  // [b][i][o], o<1024
  u16*   vbf    = (u16*)alloc((size_t)4 * NC * 2);        // [b][c][j]
  u16*   ao     = (u16*)alloc((size_t)4 * NC * 2);        // [b][i][c]
  u16*   E      = (u16*)alloc((size_t)N * N * 2);         // per-batch exp(S)
  u16*   pvpart = (u16*)alloc((size_t)4 * NC * 2);        // per-batch [z][i][c]

  cvt_weights<<<3072, 256, 0, stream>>>(w_qkv, w_proj, wq_bf, wp_bf);
  gn_stats<<<128, 256, 0, stream>>>(x, stats);
  gn_norm_t<<<dim3(64, 8, 4), 256, 0, stream>>>(x, stats, gamma, beta, xnT);
  hipMemsetAsync(rowsum, 0, (size_t)4 * N * 4, stream);

  // qkT[b][i][o] = (sum_c xnT[b][i][c]*wq[o][c] + b_qkv[o]) * scale
  gemm_nt<4><<<dim3(8, 32, 4), 256, 0, stream>>>(
      xnT, wq_bf, 512, 512, 512, b_qkv, nullptr, scale,
      nullptr, qkT, 1024, NC, 0, (size_t)N * 1024);
  // vbf[b][c][j] = sum_k wq[1024+c][k]*xnT[b][j][k] + b_qkv[1024+c]
  gemm_nt<5><<<dim3(32, 4, 4), 256, 0, stream>>>(
      wq_bf + (size_t)1024 * 512, xnT, 512, 512, 512, b_qkv + 1024, nullptr,
      0.f, nullptr, vbf, 4096, 0, NC, NC);

  for (int b = 0; b < 4; ++b) {
    const u16* qkb = qkT + (size_t)b * N * 1024;
    // E[i][j] = bf16(exp(S[i][j])), rowsum[b][i] += partials
    gemm_nt<7><<<dim3(32, 32), 256, 0, stream>>>(
        qkb, qkb + 512, 1024, 1024, 512, nullptr, nullptr, 0.f,
        rowsum + (size_t)b * N, E, 4096, 0, 0, 0);
    // pvpart[z][i][c] = sum_{j in seg z} E[i][j]*v[c][j]   (bf16)
    gemm_nt<2><<<dim3(4, 32, 4), 256, 0, stream>>>(
        E, vbf + (size_t)b * NC, 4096, 4096, 1024, nullptr, nullptr, 0.f,
        nullptr, pvpart, 512, 1024, 1024, NC);
    // ao[b][i][c] = bf16(sum_z pvpart / rowsum[b][i])
    pv_reduce<<<2048, 256, 0, stream>>>(pvpart, rowsum + (size_t)b * N,
                                        ao + (size_t)b * NC);
  }

  // out[b][o][n] = sum_c wp[o][c]*ao[b][n][c] + b_proj[o] + x[b][o][n]
  gemm_nt<3><<<dim3(32, 4, 4), 256, 0, stream>>>(
      wp_bf, ao, 512, 512, 512, b_proj, x, 0.f,
      out, nullptr, 4096, 0, NC, NC);
}

// Round 7
// 455.366 us; speedup vs baseline: 1.1688x; 1.1688x over previous
//
#include <hip/hip_runtime.h>
#include <stdint.h>

typedef unsigned short u16;
typedef __bf16 bf16x8 __attribute__((ext_vector_type(8)));
typedef float f32x4 __attribute__((ext_vector_type(4)));

__device__ __forceinline__ u16 f2bf(float f) {
  union { float f; unsigned u; } v; v.f = f;
  return (u16)((v.u + 0x7FFFu + ((v.u >> 16) & 1u)) >> 16);
}
__device__ __forceinline__ float bf2f(u16 h) {
  union { unsigned u; float f; } v; v.u = ((unsigned)h) << 16; return v.f;
}

// async 16B global -> LDS (wave-uniform LDS base; HW writes base + lane*16)
__device__ __forceinline__ void gld_lds16(const u16* g, u16* l) {
  uint32_t lo = (uint32_t)(uintptr_t)l;
  lo = __builtin_amdgcn_readfirstlane(lo);
  auto* lp = (__attribute__((address_space(3))) uint32_t*)(uintptr_t)lo;
  auto* gp = (const __attribute__((address_space(1))) uint32_t*)(uintptr_t)g;
  __builtin_amdgcn_global_load_lds(gp, lp, 16, 0, 0);
}

// ---------------- weight fp32 -> bf16 ----------------
__global__ __launch_bounds__(256) void cvt_weights(
    const float* __restrict__ wq, const float* __restrict__ wp,
    u16* __restrict__ oq, u16* __restrict__ op) {
  int i = blockIdx.x * 256 + threadIdx.x;
  if (i < 1536 * 512) oq[i] = f2bf(wq[i]);
  if (i < 512 * 512)  op[i] = f2bf(wp[i]);
}

// ---------------- group norm stats ----------------
__global__ __launch_bounds__(256) void gn_stats(const float* __restrict__ x,
                                                float* __restrict__ stats) {
  int bg = blockIdx.x;  // 0..127
  const float* p = x + (size_t)bg * 65536;
  float s = 0.f, sq = 0.f;
  for (int i = threadIdx.x * 4; i < 65536; i += 1024) {
    float4 v = *(const float4*)(p + i);
    s += v.x + v.y + v.z + v.w;
    sq += v.x * v.x + v.y * v.y + v.z * v.z + v.w * v.w;
  }
  int lane = threadIdx.x & 63, w = threadIdx.x >> 6;
  for (int off = 32; off; off >>= 1) {
    s += __shfl_down(s, off);
    sq += __shfl_down(sq, off);
  }
  __shared__ float ls[4], lq[4];
  if (lane == 0) { ls[w] = s; lq[w] = sq; }
  __syncthreads();
  if (threadIdx.x == 0) {
    float S = ls[0] + ls[1] + ls[2] + ls[3];
    float Q = lq[0] + lq[1] + lq[2] + lq[3];
    float mean = S * (1.f / 65536.f);
    float var = Q * (1.f / 65536.f) - mean * mean;
    stats[bg * 2] = mean;
    stats[bg * 2 + 1] = rsqrtf(var + 1e-6f);
  }
}

// ---------------- group norm + transpose: x[b][c][n] -> xnT[b][n][c] bf16 ----
__global__ __launch_bounds__(256) void gn_norm_t(const float* __restrict__ x,
    const float* __restrict__ stats, const float* __restrict__ gamma,
    const float* __restrict__ beta, u16* __restrict__ xnT) {
  __shared__ u16 tile[64][72];
  int b = blockIdx.z;
  int c0 = blockIdx.y * 64, n0 = blockIdx.x * 64;
  int t = threadIdx.x;
  int cl = t >> 2, ng = (t & 3) * 16;
  int c = c0 + cl;
  float mean = stats[(b * 32 + (c >> 4)) * 2];
  float rstd = stats[(b * 32 + (c >> 4)) * 2 + 1];
  float a = gamma[c] * rstd;
  float b2 = beta[c] - mean * a;
  const float* src = x + ((size_t)b * 512 + c) * 4096 + n0 + ng;
  u16 e[16];
  #pragma unroll
  for (int q = 0; q < 4; ++q) {
    float4 v = *(const float4*)(src + q * 4);
    e[q * 4 + 0] = f2bf(v.x * a + b2);
    e[q * 4 + 1] = f2bf(v.y * a + b2);
    e[q * 4 + 2] = f2bf(v.z * a + b2);
    e[q * 4 + 3] = f2bf(v.w * a + b2);
  }
  #pragma unroll
  for (int j = 0; j < 16; ++j) tile[ng + j][cl] = e[j];
  __syncthreads();
  int nl = t >> 2, cg = (t & 3) * 16;
  uint4 w0 = *(const uint4*)&tile[nl][cg];
  uint4 w1 = *(const uint4*)&tile[nl][cg + 8];
  u16* dst = xnT + ((size_t)b * 4096 + n0 + nl) * 512 + c0 + cg;
  *(uint4*)dst = w0;
  *(uint4*)(dst + 8) = w1;
}

// ---------------- unified NT GEMM: C[m][n] = sum_k A[m*lda+k]*B[n*ldb+k] ----
// 128x128 tile, BK=32, double-buffered LDS + global_load_lds.
// SWZ=1: 16x16 super-tile block swizzle (requires gridDim.x==gridDim.y==32).
// EPI: 2 = bf16 out plain (PV partial)
//      3 = fp32 out + bias[m] + resid (proj; direct epilogue)
//      4 = bf16 out, (acc+bias[n])*scale  (qk: m=spatial, n=channel)
//      5 = bf16 out, acc+bias[m]          (v:  m=channel, n=spatial)
//      6 = bf16 out, acc * rcp(rowsum[m]) (PV direct; rowsum via resid ptr)
//      7 = bf16 out exp(acc), atomicAdd row-sums into outF[m+z*4096]
template<int EPI, int SWZ>
__global__ __launch_bounds__(256) void gemm_nt(
    const u16* __restrict__ A, const u16* __restrict__ B,
    int lda, int ldb, int K,
    const float* __restrict__ bias, const float* __restrict__ resid,
    float scale, float* __restrict__ outF, u16* __restrict__ outB, int ldo,
    size_t azs, size_t bzs, size_t ozs) {
  // stages: A0 [0,4096) A1 [4096,8192) B0 [8192,12288) B1 [12288,16384) u16
  // epilogue bounce tile 128x136 overlays [0,17408)
  __shared__ __align__(16) u16 smem[17408];
  const size_t z = blockIdx.z;
  A += z * azs; B += z * bzs;
  int bx = blockIdx.x, by = blockIdx.y;
  if (SWZ) {  // 16x16 super-tiles over a 32x32 grid
    int lin = by * 32 + bx;
    int tt = lin >> 8, w = lin & 255;
    by = (tt >> 1) * 16 + (w >> 4);
    bx = (tt & 1) * 16 + (w & 15);
  }
  const int t = threadIdx.x;
  const int wave = t >> 6, lane = t & 63;
  const int wm = wave >> 1, wn = wave & 1;
  const int quad = lane >> 4, li = lane & 15;
  const int m0 = by * 128, n0 = bx * 128;

  const int srow = lane >> 2;
  const int scol = (lane & 3) * 8;
  const u16* gA[2];
  const u16* gB[2];
  int ldsOff[2];
  #pragma unroll
  for (int r = 0; r < 2; ++r) {
    int rb = wave + 4 * r;
    gA[r] = A + (size_t)(m0 + rb * 16 + srow) * lda + scol;
    gB[r] = B + (size_t)(n0 + rb * 16 + srow) * ldb + scol;
    ldsOff[r] = rb * 512;
  }

  f32x4 zero = {0.f, 0.f, 0.f, 0.f};
  f32x4 acc[4][4];
  #pragma unroll
  for (int i = 0; i < 4; ++i)
    #pragma unroll
    for (int j = 0; j < 4; ++j) acc[i][j] = zero;

  #pragma unroll
  for (int r = 0; r < 2; ++r) {
    gld_lds16(gA[r], &smem[ldsOff[r]]);
    gld_lds16(gB[r], &smem[8192 + ldsOff[r]]);
  }
  __syncthreads();

  for (int kt = 0; kt < K; kt += 32) {
    const int s = (kt >> 5) & 1;
    if (kt + 32 < K) {
      const int ns = s ^ 1;
      #pragma unroll
      for (int r = 0; r < 2; ++r) {
        gld_lds16(gA[r] + kt + 32, &smem[ns * 4096 + ldsOff[r]]);
        gld_lds16(gB[r] + kt + 32, &smem[8192 + ns * 4096 + ldsOff[r]]);
      }
    }
    bf16x8 af[4], bf[4];
    #pragma unroll
    for (int i = 0; i < 4; ++i) {
      af[i] = *(const bf16x8*)&smem[s * 4096 +
               (wm * 64 + i * 16 + li) * 32 + quad * 8];
      bf[i] = *(const bf16x8*)&smem[8192 + s * 4096 +
               (wn * 64 + i * 16 + li) * 32 + quad * 8];
    }
    #pragma unroll
    for (int i = 0; i < 4; ++i)
      #pragma unroll
      for (int j = 0; j < 4; ++j)
        acc[i][j] = __builtin_amdgcn_mfma_f32_16x16x32_bf16(
            af[i], bf[j], acc[i][j], 0, 0, 0);
    __syncthreads();
  }

  if (EPI == 3) {
    outF += z * ozs; resid += z * ozs;
    #pragma unroll
    for (int i = 0; i < 4; ++i)
      #pragma unroll
      for (int j = 0; j < 4; ++j) {
        int mB = m0 + wm * 64 + i * 16 + quad * 4;
        int n = n0 + wn * 64 + j * 16 + li;
        #pragma unroll
        for (int r = 0; r < 4; ++r) {
          int m = mB + r;
          float v = acc[i][j][r] + bias[m] + resid[(size_t)m * ldo + n];
          outF[(size_t)m * ldo + n] = v;
        }
      }
    return;
  }

  // bf16 epilogues: bounce through LDS, coalesced dwordx4 stores
  outB += z * ozs;
  if (EPI == 6) resid += z * 4096;  // rowsum
  if (EPI == 7) outF += z * 4096;   // rowsum accumulator
  #pragma unroll
  for (int i = 0; i < 4; ++i) {
    int lm = wm * 64 + i * 16 + quad * 4;
    float rs[4] = {0.f, 0.f, 0.f, 0.f};
    float rinv[4];
    if (EPI == 6) {
      #pragma unroll
      for (int r = 0; r < 4; ++r)
        rinv[r] = __builtin_amdgcn_rcpf(resid[m0 + lm + r]);
    }
    #pragma unroll
    for (int j = 0; j < 4; ++j) {
      int ln = wn * 64 + j * 16 + li;
      #pragma unroll
      for (int r = 0; r < 4; ++r) {
        float v = acc[i][j][r];
        u16 o;
        if (EPI == 2) {
          o = f2bf(v);
        } else if (EPI == 4) {
          o = f2bf((v + bias[n0 + ln]) * scale);
        } else if (EPI == 5) {
          o = f2bf(v + bias[m0 + lm + r]);
        } else if (EPI == 6) {
          o = f2bf(v * rinv[r]);
        } else {  // EPI 7
          float e = __expf(v);
          o = f2bf(e);
          rs[r] += e;
        }
        smem[(lm + r) * 136 + ln] = o;
      }
    }
    if (EPI == 7) {
      #pragma unroll
      for (int r = 0; r < 4; ++r) {
        rs[r] += __shfl_xor(rs[r], 1);
        rs[r] += __shfl_xor(rs[r], 2);
        rs[r] += __shfl_xor(rs[r], 4);
        rs[r] += __shfl_xor(rs[r], 8);
      }
      if (li == 0) {
        #pragma unroll
        for (int r = 0; r < 4; ++r) atomicAdd(&outF[m0 + lm + r], rs[r]);
      }
    }
  }
  __syncthreads();
  {
    int row = t >> 1, half = t & 1;
    const u16* src = &smem[row * 136 + half * 64];
    u16* dst = outB + (size_t)(m0 + row) * ldo + n0 + half * 64;
    #pragma unroll
    for (int cc = 0; cc < 8; ++cc)
      *(uint4*)(dst + cc * 8) = *(const uint4*)(src + cc * 8);
  }
}

// -------- PV split-K reduce (fallback path) ----------
__global__ __launch_bounds__(256) void pv_reduce(const u16* __restrict__ part,
    const float* __restrict__ rowsum, u16* __restrict__ ao) {
  size_t i = ((size_t)blockIdx.x * 256 + threadIdx.x) * 4;
  int row = (int)(i >> 9);
  float inv = __builtin_amdgcn_rcpf(rowsum[row]);
  float s0 = 0.f, s1 = 0.f, s2 = 0.f, s3 = 0.f;
  #pragma unroll
  for (int zz = 0; zz < 4; ++zz) {
    ushort4 p = *(const ushort4*)(part + (size_t)zz * 2097152 + i);
    s0 += bf2f(p.x); s1 += bf2f(p.y); s2 += bf2f(p.z); s3 += bf2f(p.w);
  }
  ushort4 o;
  o.x = f2bf(s0 * inv); o.y = f2bf(s1 * inv);
  o.z = f2bf(s2 * inv); o.w = f2bf(s3 * inv);
  *(ushort4*)(ao + i) = o;
}

extern "C" void kernel_launch(void* const* d_in, const int* in_sizes, int n_in,
                              void* d_out, int out_size, void* d_ws, size_t ws_size,
                              hipStream_t stream) {
  (void)in_sizes; (void)n_in; (void)out_size;
  const float* x      = (const float*)d_in[0];
  const float* gamma  = (const float*)d_in[1];
  const float* beta   = (const float*)d_in[2];
  const float* w_qkv  = (const float*)d_in[3];
  const float* b_qkv  = (const float*)d_in[4];
  const float* w_proj = (const float*)d_in[5];
  const float* b_proj = (const float*)d_in[6];
  float* out = (float*)d_out;

  const int C = 512, N = 4096;
  const size_t NC = (size_t)N * C;
  const float scale = 0.21022410381342863f;  // 512^-0.25

  // big path: E kept for all 4 batches; single unsplit PV. Needs ~221 MB.
  const bool big = ws_size >= (size_t)230 * 1000 * 1000;

  char* ws = (char*)d_ws;
  size_t off = 0;
  auto alloc = [&](size_t bytes) -> char* {
    char* p = ws + off; off += (bytes + 255) & ~(size_t)255; return p;
  };
  u16*   wq_bf  = (u16*)alloc((size_t)1536 * 512 * 2);
  u16*   wp_bf  = (u16*)alloc((size_t)512 * 512 * 2);
  float* stats  = (float*)alloc(128 * 2 * 4);
  float* rowsum = (float*)alloc((size_t)4 * N * 4);
  u16*   xnT    = (u16*)alloc((size_t)4 * NC * 2);        // [b][n][c]
  u16*   qkT    = (u16*)alloc((size_t)4 * N * 1024 * 2);  // [b][i][o], o<1024
  u16*   vbf    = (u16*)alloc((size_t)4 * NC * 2);        // [b][c][j]
  u16*   ao     = (u16*)alloc((size_t)4 * NC * 2);        // [b][i][c]
  u16*   E      = (u16*)alloc(((size_t)(big ? 4 : 1)) * N * N * 2);
  u16*   pvpart = big ? nullptr : (u16*)alloc((size_t)4 * NC * 2);

  cvt_weights<<<3072, 256, 0, stream>>>(w_qkv, w_proj, wq_bf, wp_bf);
  gn_stats<<<128, 256, 0, stream>>>(x, stats);
  gn_norm_t<<<dim3(64, 8, 4), 256, 0, stream>>>(x, stats, gamma, beta, xnT);
  hipMemsetAsync(rowsum, 0, (size_t)4 * N * 4, stream);

  // qkT[b][i][o] = (sum_c xnT[b][i][c]*wq[o][c] + b_qkv[o]) * scale
  gemm_nt<4, 0><<<dim3(8, 32, 4), 256, 0, stream>>>(
      xnT, wq_bf, 512, 512, 512, b_qkv, nullptr, scale,
      nullptr, qkT, 1024, NC, 0, (size_t)N * 1024);
  // vbf[b][c][j] = sum_k wq[1024+c][k]*xnT[b][j][k] + b_qkv[1024+c]
  gemm_nt<5, 0><<<dim3(32, 4, 4), 256, 0, stream>>>(
      wq_bf + (size_t)1024 * 512, xnT, 512, 512, 512, b_qkv + 1024, nullptr,
      0.f, nullptr, vbf, 4096, 0, NC, NC);

  if (big) {
    // E[b][i][j] = bf16(exp(S)), rowsum[b][i] += partials  (one dispatch)
    gemm_nt<7, 1><<<dim3(32, 32, 4), 256, 0, stream>>>(
        qkT, qkT + 512, 1024, 1024, 512, nullptr, nullptr, 0.f,
        rowsum, E, 4096, (size_t)N * 1024, (size_t)N * 1024, (size_t)N * N);
    // ao[b][i][c] = bf16((sum_j E*v) / rowsum[b][i])  (unsplit K=4096)
    gemm_nt<6, 0><<<dim3(4, 32, 4), 256, 0, stream>>>(
        E, vbf, 4096, 4096, 4096, nullptr, rowsum, 0.f,
        nullptr, ao, 512, (size_t)N * N, NC, NC);
  } else {
    for (int b = 0; b < 4; ++b) {
      const u16* qkb = qkT + (size_t)b * N * 1024;
      gemm_nt<7, 1><<<dim3(32, 32), 256, 0, stream>>>(
          qkb, qkb + 512, 1024, 1024, 512, nullptr, nullptr, 0.f,
          rowsum + (size_t)b * N, E, 4096, 0, 0, 0);
      gemm_nt<2, 0><<<dim3(4, 32, 4), 256, 0, stream>>>(
          E, vbf + (size_t)b * NC, 4096, 4096, 1024, nullptr, nullptr, 0.f,
          nullptr, pvpart, 512, 1024, 1024, NC);
      pv_reduce<<<2048, 256, 0, stream>>>(pvpart, rowsum + (size_t)b * N,
                                          ao + (size_t)b * NC);
    }
  }

  // out[b][o][n] = sum_c wp[o][c]*ao[b][n][c] + b_proj[o] + x[b][o][n]
  gemm_nt<3, 0><<<dim3(32, 4, 4), 256, 0, stream>>>(
      wp_bf, ao, 512, 512, 512, b_proj, x, 0.f,
      out, nullptr, 4096, 0, NC, NC);
}

// Round 8
// 405.512 us; speedup vs baseline: 1.3125x; 1.1229x over previous
//
#include <hip/hip_runtime.h>
#include <hip/hip_fp8.h>
#include <stdint.h>

typedef unsigned short u16;
typedef unsigned char u8;
typedef __bf16 bf16x8 __attribute__((ext_vector_type(8)));
typedef float f32x4 __attribute__((ext_vector_type(4)));

__device__ __forceinline__ u16 f2bf(float f) {
  union { float f; unsigned u; } v; v.f = f;
  return (u16)((v.u + 0x7FFFu + ((v.u >> 16) & 1u)) >> 16);
}
__device__ __forceinline__ u8 f2f8(float f) {
  __hip_fp8_e4m3 h(f);
  return (u8)h.__x;
}

// async 16B global -> LDS (wave-uniform LDS base; HW writes base + lane*16)
__device__ __forceinline__ void gld_lds16(const void* g, void* l) {
  uint32_t lo = (uint32_t)(uintptr_t)l;
  lo = __builtin_amdgcn_readfirstlane(lo);
  auto* lp = (__attribute__((address_space(3))) uint32_t*)(uintptr_t)lo;
  auto* gp = (const __attribute__((address_space(1))) uint32_t*)(uintptr_t)g;
  __builtin_amdgcn_global_load_lds(gp, lp, 16, 0, 0);
}

// ---------------- weight fp32 -> bf16 ----------------
__global__ __launch_bounds__(256) void cvt_weights(
    const float* __restrict__ wq, const float* __restrict__ wp,
    u16* __restrict__ oq, u16* __restrict__ op) {
  int i = blockIdx.x * 256 + threadIdx.x;
  if (i < 1536 * 512) oq[i] = f2bf(wq[i]);
  if (i < 512 * 512)  op[i] = f2bf(wp[i]);
}

// ---------------- group norm stats ----------------
__global__ __launch_bounds__(256) void gn_stats(const float* __restrict__ x,
                                                float* __restrict__ stats) {
  int bg = blockIdx.x;  // 0..127
  const float* p = x + (size_t)bg * 65536;
  float s = 0.f, sq = 0.f;
  for (int i = threadIdx.x * 4; i < 65536; i += 1024) {
    float4 v = *(const float4*)(p + i);
    s += v.x + v.y + v.z + v.w;
    sq += v.x * v.x + v.y * v.y + v.z * v.z + v.w * v.w;
  }
  int lane = threadIdx.x & 63, w = threadIdx.x >> 6;
  for (int off = 32; off; off >>= 1) {
    s += __shfl_down(s, off);
    sq += __shfl_down(sq, off);
  }
  __shared__ float ls[4], lq[4];
  if (lane == 0) { ls[w] = s; lq[w] = sq; }
  __syncthreads();
  if (threadIdx.x == 0) {
    float S = ls[0] + ls[1] + ls[2] + ls[3];
    float Q = lq[0] + lq[1] + lq[2] + lq[3];
    float mean = S * (1.f / 65536.f);
    float var = Q * (1.f / 65536.f) - mean * mean;
    stats[bg * 2] = mean;
    stats[bg * 2 + 1] = rsqrtf(var + 1e-6f);
  }
}

// ---------------- group norm + transpose: x[b][c][n] -> xnT[b][n][c] bf16 ----
__global__ __launch_bounds__(256) void gn_norm_t(const float* __restrict__ x,
    const float* __restrict__ stats, const float* __restrict__ gamma,
    const float* __restrict__ beta, u16* __restrict__ xnT) {
  __shared__ u16 tile[64][72];
  int b = blockIdx.z;
  int c0 = blockIdx.y * 64, n0 = blockIdx.x * 64;
  int t = threadIdx.x;
  int cl = t >> 2, ng = (t & 3) * 16;
  int c = c0 + cl;
  float mean = stats[(b * 32 + (c >> 4)) * 2];
  float rstd = stats[(b * 32 + (c >> 4)) * 2 + 1];
  float a = gamma[c] * rstd;
  float b2 = beta[c] - mean * a;
  const float* src = x + ((size_t)b * 512 + c) * 4096 + n0 + ng;
  u16 e[16];
  #pragma unroll
  for (int q = 0; q < 4; ++q) {
    float4 v = *(const float4*)(src + q * 4);
    e[q * 4 + 0] = f2bf(v.x * a + b2);
    e[q * 4 + 1] = f2bf(v.y * a + b2);
    e[q * 4 + 2] = f2bf(v.z * a + b2);
    e[q * 4 + 3] = f2bf(v.w * a + b2);
  }
  #pragma unroll
  for (int j = 0; j < 16; ++j) tile[ng + j][cl] = e[j];
  __syncthreads();
  int nl = t >> 2, cg = (t & 3) * 16;
  uint4 w0 = *(const uint4*)&tile[nl][cg];
  uint4 w1 = *(const uint4*)&tile[nl][cg + 8];
  u16* dst = xnT + ((size_t)b * 4096 + n0 + nl) * 512 + c0 + cg;
  *(uint4*)dst = w0;
  *(uint4*)(dst + 8) = w1;
}

// ------------- bf16 NT GEMM: C[m][n] = sum_k A[m*lda+k]*B[n*ldb+k] --------
// 128x128 tile, BK=32, dbuf LDS + global_load_lds.
// EPI: 3 = fp32 out + bias[m] + resid (proj)
//      4 = fp8 out, (acc+bias[n])*scale  (qk: m=spatial, n=channel)
//      5 = fp8 out, acc+bias[m]          (v:  m=channel, n=spatial)
template<int EPI>
__global__ __launch_bounds__(256) void gemm_nt(
    const u16* __restrict__ A, const u16* __restrict__ B,
    int lda, int ldb, int K,
    const float* __restrict__ bias, const float* __restrict__ resid,
    float scale, float* __restrict__ outF, void* __restrict__ outBv, int ldo,
    size_t azs, size_t bzs, size_t ozs) {
  // stages (u16 idx): A0 [0,4096) A1 [4096,8192) B0 [8192,12288) B1 [12288,16384)
  // fp8 epilogue bounce: u8 128x144 overlays [0,18432) bytes
  __shared__ __align__(16) u16 smem[16384];
  const size_t z = blockIdx.z;
  A += z * azs; B += z * bzs;
  const int t = threadIdx.x;
  const int wave = t >> 6, lane = t & 63;
  const int wm = wave >> 1, wn = wave & 1;
  const int quad = lane >> 4, li = lane & 15;
  const int m0 = blockIdx.y * 128, n0 = blockIdx.x * 128;

  const int srow = lane >> 2;
  const int scol = (lane & 3) * 8;
  const u16* gA[2];
  const u16* gB[2];
  int ldsOff[2];
  #pragma unroll
  for (int r = 0; r < 2; ++r) {
    int rb = wave + 4 * r;
    gA[r] = A + (size_t)(m0 + rb * 16 + srow) * lda + scol;
    gB[r] = B + (size_t)(n0 + rb * 16 + srow) * ldb + scol;
    ldsOff[r] = rb * 512;
  }

  f32x4 zero = {0.f, 0.f, 0.f, 0.f};
  f32x4 acc[4][4];
  #pragma unroll
  for (int i = 0; i < 4; ++i)
    #pragma unroll
    for (int j = 0; j < 4; ++j) acc[i][j] = zero;

  #pragma unroll
  for (int r = 0; r < 2; ++r) {
    gld_lds16(gA[r], &smem[ldsOff[r]]);
    gld_lds16(gB[r], &smem[8192 + ldsOff[r]]);
  }
  __syncthreads();

  for (int kt = 0; kt < K; kt += 32) {
    const int s = (kt >> 5) & 1;
    if (kt + 32 < K) {
      const int ns = s ^ 1;
      #pragma unroll
      for (int r = 0; r < 2; ++r) {
        gld_lds16(gA[r] + kt + 32, &smem[ns * 4096 + ldsOff[r]]);
        gld_lds16(gB[r] + kt + 32, &smem[8192 + ns * 4096 + ldsOff[r]]);
      }
    }
    bf16x8 af[4], bf[4];
    #pragma unroll
    for (int i = 0; i < 4; ++i) {
      af[i] = *(const bf16x8*)&smem[s * 4096 +
               (wm * 64 + i * 16 + li) * 32 + quad * 8];
      bf[i] = *(const bf16x8*)&smem[8192 + s * 4096 +
               (wn * 64 + i * 16 + li) * 32 + quad * 8];
    }
    #pragma unroll
    for (int i = 0; i < 4; ++i)
      #pragma unroll
      for (int j = 0; j < 4; ++j)
        acc[i][j] = __builtin_amdgcn_mfma_f32_16x16x32_bf16(
            af[i], bf[j], acc[i][j], 0, 0, 0);
    __syncthreads();
  }

  if (EPI == 3) {
    outF += z * ozs; resid += z * ozs;
    #pragma unroll
    for (int i = 0; i < 4; ++i)
      #pragma unroll
      for (int j = 0; j < 4; ++j) {
        int mB = m0 + wm * 64 + i * 16 + quad * 4;
        int n = n0 + wn * 64 + j * 16 + li;
        #pragma unroll
        for (int r = 0; r < 4; ++r) {
          int m = mB + r;
          float v = acc[i][j][r] + bias[m] + resid[(size_t)m * ldo + n];
          outF[(size_t)m * ldo + n] = v;
        }
      }
    return;
  }

  // fp8 outputs (EPI 4/5): bounce through LDS, coalesced stores
  u8* out8 = (u8*)outBv + z * ozs;
  u8* bnc = (u8*)smem;
  #pragma unroll
  for (int i = 0; i < 4; ++i) {
    int lm = wm * 64 + i * 16 + quad * 4;
    #pragma unroll
    for (int j = 0; j < 4; ++j) {
      int ln = wn * 64 + j * 16 + li;
      #pragma unroll
      for (int r = 0; r < 4; ++r) {
        float v = acc[i][j][r];
        u8 o;
        if (EPI == 4) o = f2f8((v + bias[n0 + ln]) * scale);
        else          o = f2f8(v + bias[m0 + lm + r]);
        bnc[(lm + r) * 144 + ln] = o;
      }
    }
  }
  __syncthreads();
  {
    int row = t >> 1, half = t & 1;
    const u8* src = &bnc[row * 144 + half * 64];
    u8* dst = out8 + (size_t)(m0 + row) * ldo + n0 + half * 64;
    #pragma unroll
    for (int cc = 0; cc < 4; ++cc)
      *(uint4*)(dst + cc * 16) = *(const uint4*)(src + cc * 16);
  }
}

// ------------- fp8 NT GEMM: C[m][n] = sum_k A[m*lda+k]*B[n*ldb+k] ---------
// 128x128 tile, BK=32 (32 B/row staging; one 1KB gld per wave per operand),
// dbuf LDS. Frags: A[m=li][k=quad*8+j] (8B ds_read_b64, conflict-free).
// EPI: 6 = bf16 out, acc * rcp(rowsum[m])  (PV)
//      7 = fp8 out exp(acc) (clamped 448), atomicAdd row-sums into outF
template<int EPI, int SWZ>
__global__ __launch_bounds__(256) void gemm_nt8(
    const u8* __restrict__ A, const u8* __restrict__ B,
    int lda, int ldb, int K,
    const float* __restrict__ rsum, float* __restrict__ outF,
    void* __restrict__ outBv, int ldo,
    size_t azs, size_t bzs, size_t ozs) {
  // stages (bytes): A0 [0,4096) A1 [4096,8192) B0 [8192,12288) B1 [12288,16384)
  // bounce overlay: EPI7 u8 128x144 = 18432; EPI6 u16 128x136 = 34816
  __shared__ __align__(16) u8 smem[(EPI == 6) ? 34816 : 18432];
  const size_t z = blockIdx.z;
  A += z * azs; B += z * bzs;
  int bx = blockIdx.x, by = blockIdx.y;
  if (SWZ) {  // 16x16 super-tiles over a 32x32 grid
    int lin = by * 32 + bx;
    int tt = lin >> 8, w = lin & 255;
    by = (tt >> 1) * 16 + (w >> 4);
    bx = (tt & 1) * 16 + (w & 15);
  }
  const int t = threadIdx.x;
  const int wave = t >> 6, lane = t & 63;
  const int wm = wave >> 1, wn = wave & 1;
  const int quad = lane >> 4, li = lane & 15;
  const int m0 = by * 128, n0 = bx * 128;

  const int srow = lane >> 1;         // 0..31
  const int scol = (lane & 1) * 16;   // byte col
  const u8* gA = A + (size_t)(m0 + wave * 32 + srow) * lda + scol;
  const u8* gB = B + (size_t)(n0 + wave * 32 + srow) * ldb + scol;
  const int ldsOff = wave * 1024;

  f32x4 zero = {0.f, 0.f, 0.f, 0.f};
  f32x4 acc[4][4];
  #pragma unroll
  for (int i = 0; i < 4; ++i)
    #pragma unroll
    for (int j = 0; j < 4; ++j) acc[i][j] = zero;

  gld_lds16(gA, &smem[ldsOff]);
  gld_lds16(gB, &smem[8192 + ldsOff]);
  __syncthreads();

  for (int kt = 0; kt < K; kt += 32) {
    const int s = (kt >> 5) & 1;
    if (kt + 32 < K) {
      const int ns = s ^ 1;
      gld_lds16(gA + kt + 32, &smem[ns * 4096 + ldsOff]);
      gld_lds16(gB + kt + 32, &smem[8192 + ns * 4096 + ldsOff]);
    }
    long af[4], bf[4];
    #pragma unroll
    for (int i = 0; i < 4; ++i) {
      af[i] = *(const long*)&smem[s * 4096 +
               (wm * 64 + i * 16 + li) * 32 + quad * 8];
      bf[i] = *(const long*)&smem[8192 + s * 4096 +
               (wn * 64 + i * 16 + li) * 32 + quad * 8];
    }
    #pragma unroll
    for (int i = 0; i < 4; ++i)
      #pragma unroll
      for (int j = 0; j < 4; ++j)
        acc[i][j] = __builtin_amdgcn_mfma_f32_16x16x32_fp8_fp8(
            af[i], bf[j], acc[i][j], 0, 0, 0);
    __syncthreads();
  }

  if (EPI == 7) {
    float* rsF = outF + z * 4096;
    u8* outE = (u8*)outBv + z * ozs;
    #pragma unroll
    for (int i = 0; i < 4; ++i) {
      int lm = wm * 64 + i * 16 + quad * 4;
      float rs[4] = {0.f, 0.f, 0.f, 0.f};
      #pragma unroll
      for (int j = 0; j < 4; ++j) {
        int ln = wn * 64 + j * 16 + li;
        #pragma unroll
        for (int r = 0; r < 4; ++r) {
          float e = fminf(__expf(acc[i][j][r]), 448.f);
          smem[(lm + r) * 144 + ln] = f2f8(e);
          rs[r] += e;
        }
      }
      #pragma unroll
      for (int r = 0; r < 4; ++r) {
        rs[r] += __shfl_xor(rs[r], 1);
        rs[r] += __shfl_xor(rs[r], 2);
        rs[r] += __shfl_xor(rs[r], 4);
        rs[r] += __shfl_xor(rs[r], 8);
      }
      if (li == 0) {
        #pragma unroll
        for (int r = 0; r < 4; ++r) atomicAdd(&rsF[m0 + lm + r], rs[r]);
      }
    }
    __syncthreads();
    int row = t >> 1, half = t & 1;
    const u8* src = &smem[row * 144 + half * 64];
    u8* dst = outE + (size_t)(m0 + row) * ldo + n0 + half * 64;
    #pragma unroll
    for (int cc = 0; cc < 4; ++cc)
      *(uint4*)(dst + cc * 16) = *(const uint4*)(src + cc * 16);
  } else {  // EPI 6: PV
    const float* rsF = rsum + z * 4096;
    u16* outp = (u16*)outBv + z * ozs;
    u16* b16 = (u16*)smem;
    #pragma unroll
    for (int i = 0; i < 4; ++i) {
      int lm = wm * 64 + i * 16 + quad * 4;
      float rinv[4];
      #pragma unroll
      for (int r = 0; r < 4; ++r)
        rinv[r] = __builtin_amdgcn_rcpf(rsF[m0 + lm + r]);
      #pragma unroll
      for (int j = 0; j < 4; ++j) {
        int ln = wn * 64 + j * 16 + li;
        #pragma unroll
        for (int r = 0; r < 4; ++r)
          b16[(lm + r) * 136 + ln] = f2bf(acc[i][j][r] * rinv[r]);
      }
    }
    __syncthreads();
    int row = t >> 1, half = t & 1;
    const u16* src = &b16[row * 136 + half * 64];
    u16* dst = outp + (size_t)(m0 + row) * ldo + n0 + half * 64;
    #pragma unroll
    for (int cc = 0; cc < 8; ++cc)
      *(uint4*)(dst + cc * 8) = *(const uint4*)(src + cc * 8);
  }
}

extern "C" void kernel_launch(void* const* d_in, const int* in_sizes, int n_in,
                              void* d_out, int out_size, void* d_ws, size_t ws_size,
                              hipStream_t stream) {
  (void)in_sizes; (void)n_in; (void)out_size; (void)ws_size;
  const float* x      = (const float*)d_in[0];
  const float* gamma  = (const float*)d_in[1];
  const float* beta   = (const float*)d_in[2];
  const float* w_qkv  = (const float*)d_in[3];
  const float* b_qkv  = (const float*)d_in[4];
  const float* w_proj = (const float*)d_in[5];
  const float* b_proj = (const float*)d_in[6];
  float* out = (float*)d_out;

  const int C = 512, N = 4096;
  const size_t NC = (size_t)N * C;
  const float scale = 0.21022410381342863f;  // 512^-0.25

  char* ws = (char*)d_ws;
  size_t off = 0;
  auto alloc = [&](size_t bytes) -> char* {
    char* p = ws + off; off += (bytes + 255) & ~(size_t)255; return p;
  };
  u16*   wq_bf  = (u16*)alloc((size_t)1536 * 512 * 2);
  u16*   wp_bf  = (u16*)alloc((size_t)512 * 512 * 2);
  float* stats  = (float*)alloc(128 * 2 * 4);
  float* rowsum = (float*)alloc((size_t)4 * N * 4);
  u16*   xnT    = (u16*)alloc((size_t)4 * NC * 2);      // [b][n][c] bf16
  u8*    qkT    = (u8*)alloc((size_t)4 * N * 1024);     // [b][i][o] fp8, o<1024
  u8*    vbf    = (u8*)alloc((size_t)4 * 512 * 4096);   // [b][c][j] fp8
  u16*   ao     = (u16*)alloc((size_t)4 * NC * 2);      // [b][i][c] bf16
  u8*    E      = (u8*)alloc((size_t)4 * N * N);        // [b][i][j] fp8

  cvt_weights<<<3072, 256, 0, stream>>>(w_qkv, w_proj, wq_bf, wp_bf);
  gn_stats<<<128, 256, 0, stream>>>(x, stats);
  gn_norm_t<<<dim3(64, 8, 4), 256, 0, stream>>>(x, stats, gamma, beta, xnT);
  hipMemsetAsync(rowsum, 0, (size_t)4 * N * 4, stream);

  // qkT[b][i][o] = fp8((sum_c xnT[b][i][c]*wq[o][c] + b_qkv[o]) * scale)
  gemm_nt<4><<<dim3(8, 32, 4), 256, 0, stream>>>(
      xnT, wq_bf, 512, 512, 512, b_qkv, nullptr, scale,
      nullptr, qkT, 1024, NC, 0, (size_t)N * 1024);
  // vbf[b][c][j] = fp8(sum_k wq[1024+c][k]*xnT[b][j][k] + b_qkv[1024+c])
  gemm_nt<5><<<dim3(32, 4, 4), 256, 0, stream>>>(
      wq_bf + (size_t)1024 * 512, xnT, 512, 512, 512, b_qkv + 1024, nullptr,
      0.f, nullptr, vbf, 4096, 0, NC, (size_t)512 * 4096);
  // E[b][i][j] = fp8(exp(S)), rowsum[b][i] += partials (one dispatch, fp8 MFMA)
  gemm_nt8<7, 1><<<dim3(32, 32, 4), 256, 0, stream>>>(
      qkT, qkT + 512, 1024, 1024, 512, nullptr, rowsum,
      E, 4096, (size_t)N * 1024, (size_t)N * 1024, (size_t)N * N);
  // ao[b][i][c] = bf16((sum_j E*v) * rcp(rowsum[b][i]))  (K=4096, fp8 MFMA)
  gemm_nt8<6, 0><<<dim3(4, 32, 4), 256, 0, stream>>>(
      E, vbf, 4096, 4096, 4096, rowsum, nullptr,
      ao, 512, (size_t)N * N, (size_t)512 * 4096, NC);
  // out[b][o][n] = sum_c wp[o][c]*ao[b][n][c] + b_proj[o] + x[b][o][n]
  gemm_nt<3><<<dim3(32, 4, 4), 256, 0, stream>>>(
      wp_bf, ao, 512, 512, 512, b_proj, x, 0.f,
      out, nullptr, 4096, 0, NC, NC);
}